// Round 3
// baseline (760.112 us; speedup 1.0000x reference)
//
#include <hip/hip_runtime.h>
#include <math.h>

#define NG  16384
#define NN  32
#define DD  128
#define RR  32
#define OO  64
#define HHH 256

// M[o][r] = sum_h Wl[o][h] * V[h][r]   (collapses readout@Wl.T into pooled@M.T)
__global__ void precompute_M_kernel(const float* __restrict__ Wl,
                                    const float* __restrict__ V,
                                    float* __restrict__ M) {
    int t = blockIdx.x * blockDim.x + threadIdx.x;   // 0..2047
    int o = t >> 5;
    int r = t & 31;
    float s = 0.f;
#pragma unroll 8
    for (int hh = 0; hh < HHH; ++hh)
        s = fmaf(Wl[o * HHH + hh], V[hh * RR + r], s);
    M[o * RR + r] = s;
}

__device__ __forceinline__ void fma4(float4& a, float s, const float4& w) {
    a.x = fmaf(s, w.x, a.x);
    a.y = fmaf(s, w.y, a.y);
    a.z = fmaf(s, w.z, a.z);
    a.w = fmaf(s, w.w, a.w);
}

// R3: direct-load structure kept (R2 killed the 5.5x DMA overfetch).
// Two new levers against the modeled non-HBM costs:
//  (a) 2 graphs fused per wave: each W ds_read_b128 now feeds both graphs'
//      FMAs -> LDS-pipe cycles halve (was ~41us chip-wide, comparable to the
//      43us HBM floor).
//  (b) rg-rotated d-walk: lane's d-quad = ((dq + rg) & 31)*4. The 8 r-group
//      lanes of each row-group read 8 CONSECUTIVE 16B chunks (128B span) in
//      the same instruction instead of 8x-duplicating one chunk -> every
//      global_load_dwordx4 covers 16 full 64B lines (1KB, zero redundancy),
//      no reliance on L1 MSHR merging across iterations. Accumulation order
//      over d is rotated per-lane, which is fine (sum is order-independent).
// W LDS reads stay conflict-free: bank = rg*4..rg*4+3 (d-row component is a
// multiple of 32 banks), broadcast across the 8 ng-duplicates.
// Occupancy 3 -> 4 blocks/CU (16KB LDS only; VGPR ~110 under the 128 cap).
__global__ __launch_bounds__(256, 4)
void gin_main_kernel(const float* __restrict__ hsrc,
                     const float* __restrict__ W,
                     const float* __restrict__ M,
                     const float* __restrict__ bl,
                     float* __restrict__ out) {
    __shared__ float sW[DD * RR];          // [d][r] row-major, 16 KB

    const int tid  = threadIdx.x;
    const int lane = tid & 63;
    const int wv   = tid >> 6;

    {   // stage W once (straight copy — same [d][r] flat layout)
        const float4* Wv  = (const float4*)W;
        float4*       sWv = (float4*)sW;
#pragma unroll
        for (int k = 0; k < 4; ++k) sWv[tid + k * 256] = Wv[tid + k * 256];
    }
    __syncthreads();   // only barrier in the kernel

    const int rg = lane & 7;      // r-group: this lane covers r = rg*4 .. rg*4+3
    const int ng = lane >> 3;     // n-group: this lane covers n = ng, ng+8, ng+16, ng+24
    const int r0 = rg * 4;
    const float* pWb = sW + r0;
    const float blv = bl[lane];

    const int wave_global = blockIdx.x * 4 + wv;   // 0..8191
    const int gA = wave_global * 2;
    const int gB = gA + 1;

    const float* haB = hsrc + (size_t)gA * (NN * DD);
    const float* hbB = hsrc + (size_t)gB * (NN * DD);
    const float* ha0 = haB + (ng +  0) * DD;
    const float* ha1 = haB + (ng +  8) * DD;
    const float* ha2 = haB + (ng + 16) * DD;
    const float* ha3 = haB + (ng + 24) * DD;
    const float* hb0 = hbB + (ng +  0) * DD;
    const float* hb1 = hbB + (ng +  8) * DD;
    const float* hb2 = hbB + (ng + 16) * DD;
    const float* hb3 = hbB + (ng + 24) * DD;

    float4 aA0 = make_float4(0.f, 0.f, 0.f, 0.f);
    float4 aA1 = aA0, aA2 = aA0, aA3 = aA0;
    float4 aB0 = aA0, aB1 = aA0, aB2 = aA0, aB3 = aA0;

    int d = rg * 4;               // rotated start; wraps mod 128
#pragma unroll 2
    for (int dq = 0; dq < 32; ++dq) {
        float4 hA0 = *(const float4*)(ha0 + d);
        float4 hA1 = *(const float4*)(ha1 + d);
        float4 hA2 = *(const float4*)(ha2 + d);
        float4 hA3 = *(const float4*)(ha3 + d);
        float4 hB0 = *(const float4*)(hb0 + d);
        float4 hB1 = *(const float4*)(hb1 + d);
        float4 hB2 = *(const float4*)(hb2 + d);
        float4 hB3 = *(const float4*)(hb3 + d);
        float4 w0 = *(const float4*)(pWb + (d + 0) * RR);
        float4 w1 = *(const float4*)(pWb + (d + 1) * RR);
        float4 w2 = *(const float4*)(pWb + (d + 2) * RR);
        float4 w3 = *(const float4*)(pWb + (d + 3) * RR);
        fma4(aA0, hA0.x, w0); fma4(aA0, hA0.y, w1); fma4(aA0, hA0.z, w2); fma4(aA0, hA0.w, w3);
        fma4(aA1, hA1.x, w0); fma4(aA1, hA1.y, w1); fma4(aA1, hA1.z, w2); fma4(aA1, hA1.w, w3);
        fma4(aA2, hA2.x, w0); fma4(aA2, hA2.y, w1); fma4(aA2, hA2.z, w2); fma4(aA2, hA2.w, w3);
        fma4(aA3, hA3.x, w0); fma4(aA3, hA3.y, w1); fma4(aA3, hA3.z, w2); fma4(aA3, hA3.w, w3);
        fma4(aB0, hB0.x, w0); fma4(aB0, hB0.y, w1); fma4(aB0, hB0.z, w2); fma4(aB0, hB0.w, w3);
        fma4(aB1, hB1.x, w0); fma4(aB1, hB1.y, w1); fma4(aB1, hB1.z, w2); fma4(aB1, hB1.w, w3);
        fma4(aB2, hB2.x, w0); fma4(aB2, hB2.y, w1); fma4(aB2, hB2.z, w2); fma4(aB2, hB2.w, w3);
        fma4(aB3, hB3.x, w0); fma4(aB3, hB3.y, w1); fma4(aB3, hB3.z, w2); fma4(aB3, hB3.w, w3);
        d = (d + 4) & 127;
    }

#pragma unroll
    for (int side = 0; side < 2; ++side) {
        // pooled[r] = prod over all 32 n: lane-local x4, then butterfly over ng lanes
        float4 p;
        if (side == 0) {
            p.x = aA0.x * aA1.x * aA2.x * aA3.x;
            p.y = aA0.y * aA1.y * aA2.y * aA3.y;
            p.z = aA0.z * aA1.z * aA2.z * aA3.z;
            p.w = aA0.w * aA1.w * aA2.w * aA3.w;
        } else {
            p.x = aB0.x * aB1.x * aB2.x * aB3.x;
            p.y = aB0.y * aB1.y * aB2.y * aB3.y;
            p.z = aB0.z * aB1.z * aB2.z * aB3.z;
            p.w = aB0.w * aB1.w * aB2.w * aB3.w;
        }
#pragma unroll
        for (int m = 8; m <= 32; m <<= 1) {
            p.x *= __shfl_xor(p.x, m);
            p.y *= __shfl_xor(p.y, m);
            p.z *= __shfl_xor(p.z, m);
            p.w *= __shfl_xor(p.w, m);
        }

        // score[o = lane] = bl[lane] + sum_r pooled[r] * M[lane][r]
        const float4* Mv = (const float4*)(M + lane * RR);
        float s = blv;
#pragma unroll
        for (int rq = 0; rq < 8; ++rq) {
            float4 pq;                       // pooled quad rq lives (a.o.) in lane rq
            pq.x = __shfl(p.x, rq);
            pq.y = __shfl(p.y, rq);
            pq.z = __shfl(p.z, rq);
            pq.w = __shfl(p.w, rq);
            float4 m4 = Mv[rq];
            s = fmaf(pq.x, m4.x, s);
            s = fmaf(pq.y, m4.y, s);
            s = fmaf(pq.z, m4.z, s);
            s = fmaf(pq.w, m4.w, s);
        }
        out[(size_t)(side == 0 ? gA : gB) * OO + lane] = s;
    }
}

extern "C" void kernel_launch(void* const* d_in, const int* in_sizes, int n_in,
                              void* d_out, int out_size, void* d_ws, size_t ws_size,
                              hipStream_t stream) {
    const float* h  = (const float*)d_in[0];   // [16384,32,128]
    const float* W  = (const float*)d_in[1];   // [128,32]
    const float* V  = (const float*)d_in[2];   // [256,32]
    const float* Wl = (const float*)d_in[3];   // [64,256]
    const float* bl = (const float*)d_in[4];   // [64]
    float* out = (float*)d_out;                // [16384,64]
    float* M   = (float*)d_ws;                 // [64,32] scratch

    precompute_M_kernel<<<8, 256, 0, stream>>>(Wl, V, M);
    gin_main_kernel<<<2048, 256, 0, stream>>>(h, W, M, bl, out);
}

// Round 8
// 457.585 us; speedup vs baseline: 1.6611x; 1.6611x over previous
//
#include <hip/hip_runtime.h>
#include <math.h>

#define NG  16384
#define NN  32
#define DD  128
#define RR  32
#define OO  64
#define HHH 256

// M[o][r] = sum_h Wl[o][h] * V[h][r]   (collapses readout@Wl.T into pooled@M.T)
__global__ void precompute_M_kernel(const float* __restrict__ Wl,
                                    const float* __restrict__ V,
                                    float* __restrict__ M) {
    int t = blockIdx.x * blockDim.x + threadIdx.x;   // 0..2047
    int o = t >> 5;
    int r = t & 31;
    float s = 0.f;
#pragma unroll 8
    for (int hh = 0; hh < HHH; ++hh)
        s = fmaf(Wl[o * HHH + hh], V[hh * RR + r], s);
    M[o * RR + r] = s;
}

__device__ __forceinline__ void fma4(float4& a, float s, const float4& w) {
    a.x = fmaf(s, w.x, a.x);
    a.y = fmaf(s, w.y, a.y);
    a.z = fmaf(s, w.z, a.z);
    a.w = fmaf(s, w.w, a.w);
}

// R4 (resubmitted unmeasured; 4x infra failure): revert R3's rg-rotated
// d-walk (it converted free intra-instruction same-address duplication into
// cross-iteration L1 thrash -> 6.3x HBM overfetch, FETCH 1.68GB). Every
// rg-lane must read ALL d of its rows, so the 8x duplication is irreducible
// — the only free place for it is same-address-same-instruction broadcast
// (coalescer merges; L1/HBM see the unique 268MB stream once). d is uniform
// across lanes again: per load inst, 8 distinct row addresses x 16B, each
// 64B line fully consumed within 4 consecutive iterations by the same lanes
// -> tight L1 temporal locality.
// Kept from R3: 2-graph fusion per d-iteration (halves the W ds_read_b128
// stream, which at 1 graph/iter costs ~41us chip-wide vs the 43us HBM
// floor) and 4 blocks/CU occupancy (16KB LDS, VGPR ~56-90).
__global__ __launch_bounds__(256, 4)
void gin_main_kernel(const float* __restrict__ hsrc,
                     const float* __restrict__ W,
                     const float* __restrict__ M,
                     const float* __restrict__ bl,
                     float* __restrict__ out) {
    __shared__ float sW[DD * RR];          // [d][r] row-major, 16 KB

    const int tid  = threadIdx.x;
    const int lane = tid & 63;
    const int wv   = tid >> 6;

    {   // stage W once (straight copy — same [d][r] flat layout)
        const float4* Wv  = (const float4*)W;
        float4*       sWv = (float4*)sW;
#pragma unroll
        for (int k = 0; k < 4; ++k) sWv[tid + k * 256] = Wv[tid + k * 256];
    }
    __syncthreads();   // only barrier in the kernel

    const int rg = lane & 7;      // r-group: this lane covers r = rg*4 .. rg*4+3
    const int ng = lane >> 3;     // n-group: this lane covers n = ng, ng+8, ng+16, ng+24
    const int r0 = rg * 4;
    const float* pWb = sW + r0;
    const float blv = bl[lane];

    const int wave_global = blockIdx.x * 4 + wv;   // 0..8191
    const int gA = wave_global * 2;
    const int gB = gA + 1;

    const float* haB = hsrc + (size_t)gA * (NN * DD);
    const float* hbB = hsrc + (size_t)gB * (NN * DD);
    const float* ha0 = haB + (ng +  0) * DD;
    const float* ha1 = haB + (ng +  8) * DD;
    const float* ha2 = haB + (ng + 16) * DD;
    const float* ha3 = haB + (ng + 24) * DD;
    const float* hb0 = hbB + (ng +  0) * DD;
    const float* hb1 = hbB + (ng +  8) * DD;
    const float* hb2 = hbB + (ng + 16) * DD;
    const float* hb3 = hbB + (ng + 24) * DD;

    float4 aA0 = make_float4(0.f, 0.f, 0.f, 0.f);
    float4 aA1 = aA0, aA2 = aA0, aA3 = aA0;
    float4 aB0 = aA0, aB1 = aA0, aB2 = aA0, aB3 = aA0;

#pragma unroll 2
    for (int dq = 0; dq < 32; ++dq) {
        const int d = dq * 4;                 // uniform across lanes (broadcast)
        float4 hA0 = *(const float4*)(ha0 + d);
        float4 hA1 = *(const float4*)(ha1 + d);
        float4 hA2 = *(const float4*)(ha2 + d);
        float4 hA3 = *(const float4*)(ha3 + d);
        float4 hB0 = *(const float4*)(hb0 + d);
        float4 hB1 = *(const float4*)(hb1 + d);
        float4 hB2 = *(const float4*)(hb2 + d);
        float4 hB3 = *(const float4*)(hb3 + d);
        float4 w0 = *(const float4*)(pWb + (d + 0) * RR);
        float4 w1 = *(const float4*)(pWb + (d + 1) * RR);
        float4 w2 = *(const float4*)(pWb + (d + 2) * RR);
        float4 w3 = *(const float4*)(pWb + (d + 3) * RR);
        fma4(aA0, hA0.x, w0); fma4(aA0, hA0.y, w1); fma4(aA0, hA0.z, w2); fma4(aA0, hA0.w, w3);
        fma4(aA1, hA1.x, w0); fma4(aA1, hA1.y, w1); fma4(aA1, hA1.z, w2); fma4(aA1, hA1.w, w3);
        fma4(aA2, hA2.x, w0); fma4(aA2, hA2.y, w1); fma4(aA2, hA2.z, w2); fma4(aA2, hA2.w, w3);
        fma4(aA3, hA3.x, w0); fma4(aA3, hA3.y, w1); fma4(aA3, hA3.z, w2); fma4(aA3, hA3.w, w3);
        fma4(aB0, hB0.x, w0); fma4(aB0, hB0.y, w1); fma4(aB0, hB0.z, w2); fma4(aB0, hB0.w, w3);
        fma4(aB1, hB1.x, w0); fma4(aB1, hB1.y, w1); fma4(aB1, hB1.z, w2); fma4(aB1, hB1.w, w3);
        fma4(aB2, hB2.x, w0); fma4(aB2, hB2.y, w1); fma4(aB2, hB2.z, w2); fma4(aB2, hB2.w, w3);
        fma4(aB3, hB3.x, w0); fma4(aB3, hB3.y, w1); fma4(aB3, hB3.z, w2); fma4(aB3, hB3.w, w3);
    }

#pragma unroll
    for (int side = 0; side < 2; ++side) {
        // pooled[r] = prod over all 32 n: lane-local x4, then butterfly over ng lanes
        float4 p;
        if (side == 0) {
            p.x = aA0.x * aA1.x * aA2.x * aA3.x;
            p.y = aA0.y * aA1.y * aA2.y * aA3.y;
            p.z = aA0.z * aA1.z * aA2.z * aA3.z;
            p.w = aA0.w * aA1.w * aA2.w * aA3.w;
        } else {
            p.x = aB0.x * aB1.x * aB2.x * aB3.x;
            p.y = aB0.y * aB1.y * aB2.y * aB3.y;
            p.z = aB0.z * aB1.z * aB2.z * aB3.z;
            p.w = aB0.w * aB1.w * aB2.w * aB3.w;
        }
#pragma unroll
        for (int m = 8; m <= 32; m <<= 1) {
            p.x *= __shfl_xor(p.x, m);
            p.y *= __shfl_xor(p.y, m);
            p.z *= __shfl_xor(p.z, m);
            p.w *= __shfl_xor(p.w, m);
        }

        // score[o = lane] = bl[lane] + sum_r pooled[r] * M[lane][r]
        const float4* Mv = (const float4*)(M + lane * RR);
        float s = blv;
#pragma unroll
        for (int rq = 0; rq < 8; ++rq) {
            float4 pq;                       // pooled quad rq lives (a.o.) in lane rq
            pq.x = __shfl(p.x, rq);
            pq.y = __shfl(p.y, rq);
            pq.z = __shfl(p.z, rq);
            pq.w = __shfl(p.w, rq);
            float4 m4 = Mv[rq];
            s = fmaf(pq.x, m4.x, s);
            s = fmaf(pq.y, m4.y, s);
            s = fmaf(pq.z, m4.z, s);
            s = fmaf(pq.w, m4.w, s);
        }
        out[(size_t)(side == 0 ? gA : gB) * OO + lane] = s;
    }
}

extern "C" void kernel_launch(void* const* d_in, const int* in_sizes, int n_in,
                              void* d_out, int out_size, void* d_ws, size_t ws_size,
                              hipStream_t stream) {
    const float* h  = (const float*)d_in[0];   // [16384,32,128]
    const float* W  = (const float*)d_in[1];   // [128,32]
    const float* V  = (const float*)d_in[2];   // [256,32]
    const float* Wl = (const float*)d_in[3];   // [64,256]
    const float* bl = (const float*)d_in[4];   // [64]
    float* out = (float*)d_out;                // [16384,64]
    float* M   = (float*)d_ws;                 // [64,32] scratch

    precompute_M_kernel<<<8, 256, 0, stream>>>(Wl, V, M);
    gin_main_kernel<<<2048, 256, 0, stream>>>(h, W, M, bl, out);
}